// Round 4
// baseline (418.209 us; speedup 1.0000x reference)
//
#include <hip/hip_runtime.h>

// Triangle multiplication (outgoing), B=1 N=512 CZ=128 C=16, f32 I/O.
// K0 pack weights f32->bf16 -> K1 proj GEMM (a,b,g; coalesced LDS epilogue)
// -> K1b transpose b planes -> K2 per-channel 512^3 bf16 GEMMs (z, f32)
// -> K3 LN+matvec+gate (f32 out).
// z MUST stay f32: LN divides by cross-channel std, amplifying bf16 absolute
// rounding (~0.25 at |z|~128) into ~0.2 output error (round-3 failure).

#define NN 512
#define PP (NN*NN)        // 262144
#define CZD 128
#define CD 16
#define LN_EPS 1e-5f

typedef unsigned short u16;
typedef __bf16 bf16x8 __attribute__((ext_vector_type(8)));
typedef float  f32x4  __attribute__((ext_vector_type(4)));

// ws layout (bytes), 100.71 MB total (same as the round-2 footprint that ran).
// b-planes are written into the Z region and are dead once transpose_b finishes;
// K2's f32 z overwrites them.
#define OFF_A   0u          // a planes: 16 x P x bf16 = 8 MB   [c][i*512+k]
#define OFF_BT  8388608u    // b^T planes: 8 MB                 [c][j*512+k]
#define OFF_Z   16777216u   // z planes f32: 16 MB [c][i*512+j]; b planes (8 MB) live here pre-K2
#define OFF_G   33554432u   // g: P x 128 x bf16 = 64 MB        [pos][cz]
#define OFF_WT  100663296u  // packed Wt[192][128] bf16
#define OFF_BC  100712448u  // bias cat [192] f32

__device__ __forceinline__ float bf2f(u16 u) {
    union { unsigned int i; float f; } v; v.i = ((unsigned int)u) << 16; return v.f;
}
__device__ __forceinline__ u16 f2bf(float f) {  // RNE
    union { float f; unsigned int i; } v; v.f = f;
    unsigned int r = (v.i + 0x7FFFu + ((v.i >> 16) & 1u)) >> 16;
    return (u16)r;
}
__device__ __forceinline__ float sigmoidf(float x) { return 1.0f / (1.0f + __expf(-x)); }

// ---------------- K0: pack Wt[192][128] bf16 (row n holds W[:,n]) + bias[192] f32
__global__ void pack_w(const float* __restrict__ Wa1, const float* __restrict__ Wa2,
                       const float* __restrict__ Wb1, const float* __restrict__ Wb2,
                       const float* __restrict__ Wg,
                       const float* __restrict__ ba1, const float* __restrict__ ba2,
                       const float* __restrict__ bb1, const float* __restrict__ bb2,
                       const float* __restrict__ bg,
                       u16* __restrict__ wt, float* __restrict__ bc) {
    int idx = blockIdx.x * 256 + threadIdx.x;           // 0..24575
    int n = idx >> 7, k = idx & 127;
    float v;
    if      (n < 16) v = Wa1[k * CD + n];
    else if (n < 32) v = Wa2[k * CD + (n - 16)];
    else if (n < 48) v = Wb1[k * CD + (n - 32)];
    else if (n < 64) v = Wb2[k * CD + (n - 48)];
    else             v = Wg [k * CZD + (n - 64)];
    wt[n * CZD + k] = f2bf(v);
    if (idx < 192) {
        float b;
        if      (idx < 16) b = ba1[idx];
        else if (idx < 32) b = ba2[idx - 16];
        else if (idx < 48) b = bb1[idx - 32];
        else if (idx < 64) b = bb2[idx - 48];
        else               b = bg [idx - 64];
        bc[idx] = b;
    }
}

// ---------------- K1: X[P,128] @ Wcat[128,192], sigmoid epilogue, coalesced stores via LDS.
// Block = 64 rows, 4 waves; wave rt owns 16-row strip x all 192 cols (12 coltiles).
__global__ __launch_bounds__(256) void proj_kernel(const float* __restrict__ x,
                                                   const u16* __restrict__ wt,
                                                   const float* __restrict__ bc,
                                                   u16* __restrict__ a_ws, u16* __restrict__ b_ws,
                                                   u16* __restrict__ g_ws) {
    __shared__ __align__(16) u16 Xl[64][136];   // 272B rows: 16B-aligned, 2-way banks
    __shared__ __align__(16) u16 at[16][72];    // a tile [c][row]
    __shared__ __align__(16) u16 btl[16][72];   // b tile [c][row]
    __shared__ __align__(16) u16 gt[64][136];   // g tile [row][cz]
    const int t = threadIdx.x;
    const int rt = t >> 6, lane = t & 63, l16 = lane & 15, quad = lane >> 4;
    const long R0 = (long)blockIdx.x * 64;

    // stage X 64x128 f32 -> bf16
#pragma unroll
    for (int i = 0; i < 4; ++i) {
        int ch = t + 256 * i;                  // 1024 chunks of 8
        int r = ch >> 4, ko = (ch & 15) << 3;
        const float* xp = x + (R0 + r) * CZD + ko;
        const float4 v0 = *reinterpret_cast<const float4*>(xp);
        const float4 v1 = *reinterpret_cast<const float4*>(xp + 4);
        u16 tmp[8] = { f2bf(v0.x), f2bf(v0.y), f2bf(v0.z), f2bf(v0.w),
                       f2bf(v1.x), f2bf(v1.y), f2bf(v1.z), f2bf(v1.w) };
        *reinterpret_cast<uint4*>(&Xl[r][ko]) = *reinterpret_cast<const uint4*>(tmp);
    }
    // hoist biases (L2-hot)
    const float bA1 = bc[l16], bA2 = bc[16 + l16], bB1 = bc[32 + l16], bB2 = bc[48 + l16];
    float bG[8];
#pragma unroll
    for (int c2 = 0; c2 < 8; ++c2) bG[c2] = bc[64 + c2 * 16 + l16];
    __syncthreads();

    f32x4 acc[12];
#pragma unroll
    for (int ct = 0; ct < 12; ++ct) acc[ct] = (f32x4){0.f, 0.f, 0.f, 0.f};
#pragma unroll
    for (int ks = 0; ks < 4; ++ks) {
        bf16x8 af = *reinterpret_cast<const bf16x8*>(&Xl[rt * 16 + l16][ks * 32 + quad * 8]);
#pragma unroll
        for (int ct = 0; ct < 12; ++ct) {
            bf16x8 wf = *reinterpret_cast<const bf16x8*>(wt + (ct * 16 + l16) * CZD + ks * 32 + quad * 8);
            acc[ct] = __builtin_amdgcn_mfma_f32_16x16x32_bf16(af, wf, acc[ct], 0, 0, 0);
        }
    }

    // epilogue -> LDS tiles
#pragma unroll
    for (int r = 0; r < 4; ++r) {
        int row = rt * 16 + quad * 4 + r;
        float av = sigmoidf((acc[0][r] + bA1) * (acc[1][r] + bA2));
        float bv = sigmoidf((acc[2][r] + bB1) * (acc[3][r] + bB2));
        at[l16][row]  = f2bf(av);
        btl[l16][row] = f2bf(bv);
#pragma unroll
        for (int c2 = 0; c2 < 8; ++c2)
            gt[row][c2 * 16 + l16] = f2bf(sigmoidf(acc[4 + c2][r] + bG[c2]));
    }
    __syncthreads();

    // cooperative coalesced stores
    if (t < 128) {
        int c = t >> 3, ch = t & 7;
        *reinterpret_cast<uint4*>(a_ws + (long)c * PP + R0 + ch * 8) =
            *reinterpret_cast<const uint4*>(&at[c][ch * 8]);
    } else {
        int c = (t - 128) >> 3, ch = (t - 128) & 7;
        *reinterpret_cast<uint4*>(b_ws + (long)c * PP + R0 + ch * 8) =
            *reinterpret_cast<const uint4*>(&btl[c][ch * 8]);
    }
#pragma unroll
    for (int i = 0; i < 4; ++i) {
        int ch = t + 256 * i;                  // 1024 chunks: 64 rows x 16 chunks
        int row = ch >> 4, co = (ch & 15) << 3;
        *reinterpret_cast<uint4*>(g_ws + (R0 + row) * CZD + co) =
            *reinterpret_cast<const uint4*>(&gt[row][co]);
    }
}

// ---------------- K1b: transpose b planes (b[c][k][j] -> bt[c][j][k]), 64x64 tiles, swizzled LDS
__global__ __launch_bounds__(256) void transpose_b(const u16* __restrict__ b_ws,
                                                   u16* __restrict__ bt_ws) {
    __shared__ __align__(16) u16 T[64][72];
    const int t = threadIdx.x;
    const int c = blockIdx.y;
    const int ty = blockIdx.x >> 3, tx = blockIdx.x & 7;
    const int r0 = ty * 64, c0 = tx * 64;
    const u16* Bp = b_ws + (long)c * PP;
    u16* Tp = bt_ws + (long)c * PP;
#pragma unroll
    for (int i = 0; i < 2; ++i) {
        int ch = t + 256 * i;
        int r = ch >> 3, cc = ch & 7;
        uint4 v = *reinterpret_cast<const uint4*>(Bp + (long)(r0 + r) * NN + c0 + cc * 8);
        *reinterpret_cast<uint4*>(&T[r][(cc ^ (r >> 3)) << 3]) = v;
    }
    __syncthreads();
#pragma unroll
    for (int i = 0; i < 2; ++i) {
        int ch = t + 256 * i;
        int j = ch >> 3, s = ch & 7;           // output row c0+j, k-octet s
        u16 tmp[8];
#pragma unroll
        for (int m = 0; m < 8; ++m) {
            int row = s * 8 + m;
            int col = (((j >> 3) ^ s) << 3) + (j & 7);
            tmp[m] = T[row][col];
        }
        *reinterpret_cast<uint4*>(Tp + (long)(c0 + j) * NN + r0 + s * 8) =
            *reinterpret_cast<const uint4*>(tmp);
    }
}

// ---------------- K2: per-channel Z_c = A_c @ B_c, 128x128 block tile, wave = 64x64, BK=64.
// Both operands row-wise (bt gives B columns contiguous); register prefetch of next tile.
__global__ __launch_bounds__(256) void tri_kernel(const u16* __restrict__ a_ws,
                                                  const u16* __restrict__ bt_ws,
                                                  float* __restrict__ z_ws) {
    __shared__ __align__(16) u16 As[128][72];
    __shared__ __align__(16) u16 Bs[128][72];
    const int t = threadIdx.x;
    const int w = t >> 6, lane = t & 63, l16 = lane & 15, quad = lane >> 4;
    const int wr = w >> 1, wc = w & 1;
    const int c = blockIdx.y;
    const int i0 = (blockIdx.x >> 2) * 128, j0 = (blockIdx.x & 3) * 128;
    const u16* Ap = a_ws + (long)c * PP;
    const u16* Bp = bt_ws + (long)c * PP;
    const int rb = t >> 3, ko0 = (t & 7) << 3;

    f32x4 acc[4][4];
#pragma unroll
    for (int i = 0; i < 4; ++i)
#pragma unroll
        for (int j = 0; j < 4; ++j) acc[i][j] = (f32x4){0.f, 0.f, 0.f, 0.f};

    uint4 ar[4], br[4];
#pragma unroll
    for (int i = 0; i < 4; ++i) {
        int r = rb + 32 * i;
        ar[i] = *reinterpret_cast<const uint4*>(Ap + (long)(i0 + r) * NN + ko0);
        br[i] = *reinterpret_cast<const uint4*>(Bp + (long)(j0 + r) * NN + ko0);
    }
    for (int kt = 0; kt < 8; ++kt) {
#pragma unroll
        for (int i = 0; i < 4; ++i) {
            int r = rb + 32 * i;
            *reinterpret_cast<uint4*>(&As[r][ko0]) = ar[i];
            *reinterpret_cast<uint4*>(&Bs[r][ko0]) = br[i];
        }
        __syncthreads();
        if (kt < 7) {
            int k0 = (kt + 1) * 64;
#pragma unroll
            for (int i = 0; i < 4; ++i) {
                int r = rb + 32 * i;
                ar[i] = *reinterpret_cast<const uint4*>(Ap + (long)(i0 + r) * NN + k0 + ko0);
                br[i] = *reinterpret_cast<const uint4*>(Bp + (long)(j0 + r) * NN + k0 + ko0);
            }
        }
#pragma unroll
        for (int kk = 0; kk < 2; ++kk) {
            bf16x8 afr[4], bfr[4];
#pragma unroll
            for (int i = 0; i < 4; ++i) {
                afr[i] = *reinterpret_cast<const bf16x8*>(&As[wr * 64 + i * 16 + l16][kk * 32 + quad * 8]);
                bfr[i] = *reinterpret_cast<const bf16x8*>(&Bs[wc * 64 + i * 16 + l16][kk * 32 + quad * 8]);
            }
#pragma unroll
            for (int ri = 0; ri < 4; ++ri)
#pragma unroll
                for (int ci = 0; ci < 4; ++ci)
                    acc[ri][ci] = __builtin_amdgcn_mfma_f32_16x16x32_bf16(afr[ri], bfr[ci], acc[ri][ci], 0, 0, 0);
        }
        __syncthreads();
    }
    float* Zp = z_ws + (long)c * PP;
#pragma unroll
    for (int ri = 0; ri < 4; ++ri)
#pragma unroll
        for (int ci = 0; ci < 4; ++ci)
#pragma unroll
            for (int r = 0; r < 4; ++r)
                Zp[(long)(i0 + wr * 64 + ri * 16 + quad * 4 + r) * NN + j0 + wc * 64 + ci * 16 + l16] =
                    acc[ri][ci][r];
}

// ---------------- K3: out[pos][cz] = g[pos][cz] * (LN(z[pos][:]) @ Wz + bz)[cz], f32 out
__global__ __launch_bounds__(256) void out_kernel(const float* __restrict__ z_ws,
                                                  const u16* __restrict__ g_ws,
                                                  const float* __restrict__ Wz, const float* __restrict__ bz,
                                                  const float* __restrict__ lng, const float* __restrict__ lnb,
                                                  float* __restrict__ out) {
    __shared__ __align__(16) float zt[16][72];
    __shared__ __align__(16) float nl[64][20];
    __shared__ __align__(16) float wz[16][128];
    __shared__ float bzl[128];
    __shared__ float lg[16], lb[16];
    const int t = threadIdx.x;
    const long pos0 = (long)blockIdx.x * 64;

    {   // stage z: 16 channel-planes x 64 consecutive positions, coalesced float4
        int cc = t >> 4, off = (t & 15) << 2;
        const float4 v = *reinterpret_cast<const float4*>(z_ws + (long)cc * PP + pos0 + off);
        *reinterpret_cast<float4*>(&zt[cc][off]) = v;
    }
#pragma unroll
    for (int i = 0; i < 8; ++i) {
        int idx = t + 256 * i;                 // 2048 = 16*128
        wz[idx >> 7][idx & 127] = Wz[idx];
    }
    if (t < 128)      bzl[t] = bz[t];
    else if (t < 144) lg[t - 128] = lng[t - 128];
    else if (t < 160) lb[t - 144] = lnb[t - 144];
    __syncthreads();

    {   // LN over 16 channels; thread (p = t&63, cgr = t>>6) normalizes 4 channels
        int p = t & 63, cgr = t >> 6;
        float m = 0.f;
#pragma unroll
        for (int c0 = 0; c0 < 16; ++c0) m += zt[c0][p];
        m *= (1.f / 16.f);
        float v = 0.f;
#pragma unroll
        for (int c0 = 0; c0 < 16; ++c0) { float d = zt[c0][p] - m; v += d * d; }
        v *= (1.f / 16.f);
        float s = rsqrtf(v + LN_EPS);
#pragma unroll
        for (int cc = 0; cc < 4; ++cc) {
            int c0 = cgr * 4 + cc;
            nl[p][c0] = (zt[c0][p] - m) * s * lg[c0] + lb[c0];
        }
    }
    __syncthreads();

    const int cz = t & 127, pg = t >> 7;
    float wzr[16];
#pragma unroll
    for (int c0 = 0; c0 < 16; ++c0) wzr[c0] = wz[c0][cz];
    const float bzv = bzl[cz];
#pragma unroll
    for (int pp2 = 0; pp2 < 32; ++pp2) {
        int p = pg * 32 + pp2;
        const float4* np = reinterpret_cast<const float4*>(&nl[p][0]);
        float y = bzv;
#pragma unroll
        for (int c4 = 0; c4 < 4; ++c4) {
            float4 nv = np[c4];
            y += nv.x * wzr[c4 * 4 + 0] + nv.y * wzr[c4 * 4 + 1] +
                 nv.z * wzr[c4 * 4 + 2] + nv.w * wzr[c4 * 4 + 3];
        }
        long o = (pos0 + p) * CZD + cz;
        float gv = bf2f(g_ws[o]);
        out[o] = gv * y;
    }
}

extern "C" void kernel_launch(void* const* d_in, const int* in_sizes, int n_in,
                              void* d_out, int out_size, void* d_ws, size_t ws_size,
                              hipStream_t stream) {
    const float* x   = (const float*)d_in[0];
    const float* Wa1 = (const float*)d_in[1];
    const float* ba1 = (const float*)d_in[2];
    const float* Wa2 = (const float*)d_in[3];
    const float* ba2 = (const float*)d_in[4];
    const float* Wb1 = (const float*)d_in[5];
    const float* bb1 = (const float*)d_in[6];
    const float* Wb2 = (const float*)d_in[7];
    const float* bb2 = (const float*)d_in[8];
    const float* lng = (const float*)d_in[9];
    const float* lnb = (const float*)d_in[10];
    const float* Wg  = (const float*)d_in[11];
    const float* bg  = (const float*)d_in[12];
    const float* Wz  = (const float*)d_in[13];
    const float* bz  = (const float*)d_in[14];
    float* out = (float*)d_out;
    char* ws = (char*)d_ws;
    u16*   a_ws  = (u16*)(ws + OFF_A);
    u16*   bt_ws = (u16*)(ws + OFF_BT);
    u16*   b_ws  = (u16*)(ws + OFF_Z);     // b planes live in Z region until K2 overwrites
    float* z_ws  = (float*)(ws + OFF_Z);
    u16*   g_ws  = (u16*)(ws + OFF_G);
    u16*   wt    = (u16*)(ws + OFF_WT);
    float* bc    = (float*)(ws + OFF_BC);

    hipLaunchKernelGGL(pack_w, dim3(96), dim3(256), 0, stream,
                       Wa1, Wa2, Wb1, Wb2, Wg, ba1, ba2, bb1, bb2, bg, wt, bc);
    hipLaunchKernelGGL(proj_kernel, dim3(4096), dim3(256), 0, stream, x, wt, bc, a_ws, b_ws, g_ws);
    hipLaunchKernelGGL(transpose_b, dim3(64, 16), dim3(256), 0, stream, b_ws, bt_ws);
    hipLaunchKernelGGL(tri_kernel, dim3(16, 16), dim3(256), 0, stream, a_ws, bt_ws, z_ws);
    hipLaunchKernelGGL(out_kernel, dim3(4096), dim3(256), 0, stream, z_ws, g_ws, Wz, bz, lng, lnb, out);
}